// Round 8
// baseline (111.307 us; speedup 1.0000x reference)
//
#include <hip/hip_runtime.h>
#include <cstdint>

#define T_TOK 2048
#define NH 8
#define QM 4
#define DH 128
#define BQ 32             // queries per workgroup; 4 waves x 2 row-tiles = 128 rows
#define QS 136            // q_s row stride (shorts): 272B, 16B-mult
#define PS 40             // p_s row stride (shorts): 80B, 16B-mult
#define SM_SCALE 0.08838834764831845f

typedef __attribute__((ext_vector_type(8))) short short8v;   // 8 bf16 = 4 VGPR
typedef __attribute__((ext_vector_type(4))) short short4v;
typedef __attribute__((ext_vector_type(2))) short short2v;
typedef __attribute__((ext_vector_type(4))) float floatx4;

static __device__ __forceinline__ short f2bf(float x) {      // RNE float->bf16
  union { float f; unsigned u; } v; v.f = x;
  return (short)((v.u + 0x7fffu + ((v.u >> 16) & 1u)) >> 16);
}

// ---------------- prologue: K,V -> bf16 in FRAGMENT-MAJOR order -------------
// Kf[h][tile(128)][s(4)][lane(64)][8]  = K[tile*16+l16][h][quad*8+32s+j]
// Vf[h][chunk(64)][nt(8)][lane(64)][8] = V[chunk*32+key][h][l16+16nt],
//    key = quad*4 + (j>>1) + 16*(j&1)   (slot permutation baked in)
// blocks 0..255: K via LDS reshape; blocks 256..767: V direct gather (no LDS)
__global__ __launch_bounds__(256)
void preconvert(const float* __restrict__ K, const float* __restrict__ V,
                short* __restrict__ Kf, short* __restrict__ Vf) {
  __shared__ __align__(16) short lt[64][136];
  const int b = blockIdx.x, t = threadIdx.x;
  const int lane = t & 63, quad = (t >> 4) & 3, l16 = t & 15;

  if (b < 256) {                                 // ---- K path ----
    const int h = b & 7, t0 = (b >> 3) << 6;     // 64-token group
    {  // coalesced load + convert into LDS tile [tok][dim]
      const int tt = t >> 2, d0 = (t & 3) * 32;
      const float* src = K + ((size_t)(t0 + tt) * NH + h) * DH + d0;
#pragma unroll
      for (int u = 0; u < 8; ++u) {
        float4 x = *(const float4*)(src + 4 * u);
        short4v s4;
        s4[0] = f2bf(x.x); s4[1] = f2bf(x.y); s4[2] = f2bf(x.z); s4[3] = f2bf(x.w);
        *(short4v*)(&lt[tt][d0 + 4 * u]) = s4;
      }
    }
    __syncthreads();
    const int s = t >> 6;                        // 0..3
#pragma unroll
    for (int T = 0; T < 4; ++T) {
      short8v o = *(const short8v*)(&lt[T * 16 + l16][quad * 8 + s * 32]);
      short* dst = Kf + ((((size_t)h * 128 + (t0 >> 4) + T) * 4 + s) * 64 + lane) * 8;
      *(short8v*)dst = o;
    }
  } else {                                       // ---- V path: direct ----
    const int bb = b - 256;                      // 0..511
    const int h = bb & 7, c = bb >> 3;           // chunk 0..63
    const int u = t >> 6;                        // 0..3
    const float* vb = V + (size_t)(c * 32) * (NH * DH) + h * DH;
#pragma unroll
    for (int p = 0; p < 2; ++p) {
      const int nt = u + 4 * p;
      short8v o;
#pragma unroll
      for (int j = 0; j < 8; ++j) {
        const int key = quad * 4 + (j >> 1) + 16 * (j & 1);   // slot-permuted
        o[j] = f2bf(vb[(size_t)key * (NH * DH) + l16 + 16 * nt]);
      }
      *(short8v*)(Vf + ((((size_t)h * 64 + c) * 8 + nt) * 64 + lane) * 8) = o;
    }
  }
}

// -------- main: barrier-free streaming, 2 row-tiles/wave, reg-pipelined -----
__global__ __launch_bounds__(256, 2)
void attn_fwd(const float* __restrict__ Qp, const short* __restrict__ Kf,
              const short* __restrict__ Vf, const float* __restrict__ Sp,
              float* __restrict__ Op) {
  __shared__ __align__(16) short q_s[128 * QS];  // Q block bf16 [row][dim]
  __shared__ __align__(16) short p_s[128 * PS];  // exp-weights (wave-private rows)

  const int t    = threadIdx.x;
  const int lane = t & 63;
  const int wv   = t >> 6;               // 0..3
  const int quad = lane >> 4;
  const int l16  = lane & 15;

  const int bx = blockIdx.x;
  const int h  = bx & 7;                 // head == XCD -> K/V L2 locality
  const int q0 = (bx >> 3) * BQ;
  int lo0 = q0 > 127 ? q0 - 127 : 0;
  lo0 &= ~31;                            // 32-aligned base; old keys masked below
  const int nk  = q0 + BQ - lo0;         // <= 190
  const int nch = (nk + 31) >> 5;        // 1..6 (block-uniform)

  // ---- stage Q block -> LDS bf16 (fully coalesced) ----
  {
    const float* qsrc = Qp + ((size_t)q0 * 32 + h * 4) * 128;  // 32 segs of 512 fl
#pragma unroll
    for (int p = 0; p < 16; ++p) {
      const int g = t + p * 256;         // float4 id 0..4095
      const int seg = g >> 7, w = g & 127;
      const float4 x = *(const float4*)(qsrc + (size_t)seg * 4096 + w * 4);
      short4v s4;
      s4[0] = f2bf(x.x); s4[1] = f2bf(x.y); s4[2] = f2bf(x.z); s4[3] = f2bf(x.w);
      *(short4v*)(&q_s[(seg * 4 + (w >> 5)) * QS + (w & 31) * 4]) = s4;
    }
  }
  __syncthreads();                       // the ONLY barrier

  // ---- A-frags for 2 row-tiles (rows wv*32 + T*16 + l16) ----
  short8v qf[2][4];
#pragma unroll
  for (int T = 0; T < 2; ++T)
#pragma unroll
    for (int s = 0; s < 4; ++s)
      qf[T][s] = *(const short8v*)(&q_s[(wv * 32 + T * 16 + l16) * QS + quad * 8 + 32 * s]);

  float dn[2][4];
#pragma unroll
  for (int T = 0; T < 2; ++T)
#pragma unroll
    for (int r = 0; r < 4; ++r) dn[T][r] = 0.f;
  floatx4 oacc[2][8];
#pragma unroll
  for (int T = 0; T < 2; ++T)
#pragma unroll
    for (int nt = 0; nt < 8; ++nt) oacc[T][nt] = (floatx4)0.0f;

  const short* kfb = Kf + (((size_t)h * 128 + (lo0 >> 4)) * 4 * 64 + lane) * 8;
  const short* vfb = Vf + (((size_t)h * 64 + (lo0 >> 5)) * 8 * 64 + lane) * 8;

  // ---- register prefetch: K frags of chunk 0 ----
  short8v kr[8];
#pragma unroll
  for (int s = 0; s < 4; ++s) {
    kr[s]     = *(const short8v*)(kfb + s * 512);
    kr[4 + s] = *(const short8v*)(kfb + 2048 + s * 512);
  }

  for (int c = 0; c < nch; ++c) {
    const int kb = lo0 + c * 32;
    const short* vf = vfb + (size_t)c * 4096;    // 8 nt x 64 x 8

    // ---- V frags issued NOW, consumed after exp (overlap QK+softmax) ----
    short8v vr[8];
#pragma unroll
    for (int nt = 0; nt < 8; ++nt) vr[nt] = *(const short8v*)(vf + nt * 512);

    // ---- QK^T from prefetched K regs: 16 MFMA ----
    floatx4 sc[2][2];
    sc[0][0] = (floatx4)0.0f; sc[0][1] = (floatx4)0.0f;
    sc[1][0] = (floatx4)0.0f; sc[1][1] = (floatx4)0.0f;
#pragma unroll
    for (int s = 0; s < 4; ++s) {
      sc[0][0] = __builtin_amdgcn_mfma_f32_16x16x32_bf16(qf[0][s], kr[s],     sc[0][0], 0, 0, 0);
      sc[0][1] = __builtin_amdgcn_mfma_f32_16x16x32_bf16(qf[0][s], kr[4 + s], sc[0][1], 0, 0, 0);
      sc[1][0] = __builtin_amdgcn_mfma_f32_16x16x32_bf16(qf[1][s], kr[s],     sc[1][0], 0, 0, 0);
      sc[1][1] = __builtin_amdgcn_mfma_f32_16x16x32_bf16(qf[1][s], kr[4 + s], sc[1][1], 0, 0, 0);
    }

    // ---- prefetch K frags for chunk c+1 (overlaps exp + PV) ----
    if (c + 1 < nch) {
      const short* kfn = kfb + (size_t)(c + 1) * 4096;
#pragma unroll
      for (int s = 0; s < 4; ++s) {
        kr[s]     = *(const short8v*)(kfn + s * 512);
        kr[4 + s] = *(const short8v*)(kfn + 2048 + s * 512);
      }
    }

    // ---- mask + exp + packed p_s writes ----
    const int k0i = kb + l16, k1i = kb + 16 + l16;
#pragma unroll
    for (int T = 0; T < 2; ++T) {
      const int qc = q0 + 8 * wv + 4 * T + quad;
      const bool ok0 = (k0i <= qc) && (k0i > qc - 128);
      const bool ok1 = (k1i <= qc) && (k1i > qc - 128);
      const int Rb = wv * 32 + T * 16 + quad * 4;
#pragma unroll
      for (int r = 0; r < 4; ++r) {
        float e0 = ok0 ? __expf(sc[T][0][r] * SM_SCALE) : 0.f;
        float e1 = ok1 ? __expf(sc[T][1][r] * SM_SCALE) : 0.f;
        dn[T][r] += e0 + e1;
        short2v p2; p2[0] = f2bf(e0); p2[1] = f2bf(e1);
        *(short2v*)(&p_s[(Rb + r) * PS + 2 * l16]) = p2;
      }
    }

    // ---- PV from prefetched V regs ----
    short8v pf0 = *(const short8v*)(&p_s[(wv * 32 + l16) * PS + quad * 8]);
    short8v pf1 = *(const short8v*)(&p_s[(wv * 32 + 16 + l16) * PS + quad * 8]);
#pragma unroll
    for (int nt = 0; nt < 8; ++nt) {
      oacc[0][nt] = __builtin_amdgcn_mfma_f32_16x16x32_bf16(pf0, vr[nt], oacc[0][nt], 0, 0, 0);
      oacc[1][nt] = __builtin_amdgcn_mfma_f32_16x16x32_bf16(pf1, vr[nt], oacc[1][nt], 0, 0, 0);
    }
  }

  // ---- epilogue: reduce denoms across 16 col-lanes, add sink, store ----
#pragma unroll
  for (int T = 0; T < 2; ++T) {
    const int qc = q0 + 8 * wv + 4 * T + quad;
#pragma unroll
    for (int r = 0; r < 4; ++r) {
      float s = dn[T][r];
#pragma unroll
      for (int mm = 1; mm <= 8; mm <<= 1) s += __shfl_xor(s, mm);
      const float total = s + __expf(Sp[h * QM + r]);   // sink column
      const float rd = 1.0f / total;
      float* ob = Op + (size_t)qc * 4096 + (h * 4 + r) * 128 + l16;
#pragma unroll
      for (int nt = 0; nt < 8; ++nt) ob[nt * 16] = oacc[T][nt][r] * rd;
    }
  }
}

extern "C" void kernel_launch(void* const* d_in, const int* in_sizes, int n_in,
                              void* d_out, int out_size, void* d_ws, size_t ws_size,
                              hipStream_t stream) {
  const float* Q = (const float*)d_in[0];
  const float* K = (const float*)d_in[1];
  const float* V = (const float*)d_in[2];
  const float* S = (const float*)d_in[3];
  float* O = (float*)d_out;
  short* Kf = (short*)d_ws;                        // 4 MB fragment-major K
  short* Vf = Kf + (size_t)8 * 128 * 4 * 64 * 8;   // 4 MB fragment-major V

  preconvert<<<dim3(768), dim3(256), 0, stream>>>(K, V, Kf, Vf);
  const int grid = (T_TOK / BQ) * NH;              // 512 workgroups = 2/CU
  attn_fwd<<<dim3(grid), dim3(256), 0, stream>>>(Q, Kf, Vf, S, O);
}